// Round 6
// baseline (277.162 us; speedup 1.0000x reference)
//
#include <hip/hip_runtime.h>
#include <math.h>

// Problem constants (fixed by reference)
#define NF 8
#define NK 16
#define BB 32
#define YY 32
#define XX 32
#define PP 16
#define TT 8
#define YX (YY*XX)     // 1024
#define PT (PP*TT)     // 128
#define YXPT (YX*PT)   // 131072
#define CHUNKS 8
#define COLS_PER_BLOCK (YX/CHUNKS)        // 128
#define COLS_PER_WAVE  (COLS_PER_BLOCK/4) // 32
#define STEP           ((2*PT)/4)         // 64 float4s = 2 columns
#define QMEAN_BLOCKS   1024

// Workspace layout (float offsets)
#define QMEAN_OFF 0                            // [YXPT]             = 131072
#define ACC_OFF   (QMEAN_OFF + YXPT)           // [CHUNKS][BB*NF*NK] = 32768
#define INTG_OFF  (ACC_OFF + CHUNKS*BB*NF*NK)  // [4][NF*NK]         = 512

// ---------------------------------------------------------------------------
// K1 (fused): blocks 0..1023 -> qmean role; blocks 1024..3071 -> main role.
//
//  WHY FUSED (R6): k_main is latency-bound (VALUBusy ~21%, HBM ~35%, both
//  pipes idle 2/3 of the time). k_qmean (~8us + launch gap) is independent
//  of the main contraction -- only k_integral consumes qmean. Its blocks are
//  placed FIRST so they drain in ~3us and main blocks flood the machine.
//
//  DISTANCE-8 PIPELINE (R6): the R3-R5 distance-4 pipe covers only
//  4 x ~136 = 544 cyc of a ~900-cyc HBM load latency -> every wave stalls
//  in vmcnt for the last ~350 cyc regardless of occupancy (R5's occupancy
//  squeeze moved nothing: -1.8us). Distance-8 = 16 outstanding 16B
//  loads/lane = 1088 cyc coverage > 900: a SOLO wave self-covers, so this
//  is robust to whichever VGPR/occupancy bucket the allocator picks.
//  Live-set tally ~130 (bufs 64 + acc 16 + addr/temps ~50). If WRITE_SIZE
//  reappears at MB-scale, this overflowed ~200 and must drop to distance-6.
//
//  Carried verified decisions:
//  - __launch_bounds__(256) PLAIN. (256,3) produced an ~84-VGPR cap and
//    spilled wf -> 134 MB scratch writes (R1/R2). Do NOT re-add.
//  - Horner/separability: dot(ga, wf[k]) = c_k * Horner(ga, r_k); r[k]
//    wave-uniform -> SGPR via readfirstlane; c_k applied in epilogue from
//    LDS (never live across the loop). (R4/R5-verified numerics.)
//  - XCD-aware remap: 8 f-sharers of one quad slice -> same XCD L2
//    (R2-verified: FETCH 139.5 MB ~= ideal). The +1024 role offset is
//    divisible by 8, so the XCD phase of bx%8 is preserved.
//  - sw/wptab/prm tables built inline in LDS (verified numerics).
//  - plain loads only (nontemporal bypasses L2 merging -> 8x over-fetch).
// ---------------------------------------------------------------------------

#define KQ(WC, K) do {                                                          \
    float poly = fmaf(ga.w, r[K], ga.z);                                        \
    poly = fmaf(poly, r[K], ga.y);                                              \
    poly = fmaf(poly, r[K], ga.x);                                              \
    acc[K] = fmaf(WC, poly, acc[K]);                                            \
} while (0)

#define COLPAIR_COMPUTE(WVP) do {                                               \
    float4 ga;                                                                  \
    ga.x = fa.x*qa.x; ga.y = fa.y*qa.y; ga.z = fa.z*qa.z; ga.w = fa.w*qa.w;     \
    float4 w0 = (WVP)[0], w1 = (WVP)[1], w2 = (WVP)[2], w3 = (WVP)[3];          \
    KQ(w0.x, 0);  KQ(w0.y, 1);  KQ(w0.z, 2);  KQ(w0.w, 3);                      \
    KQ(w1.x, 4);  KQ(w1.y, 5);  KQ(w1.z, 6);  KQ(w1.w, 7);                      \
    KQ(w2.x, 8);  KQ(w2.y, 9);  KQ(w2.z, 10); KQ(w2.w, 11);                     \
    KQ(w3.x, 12); KQ(w3.y, 13); KQ(w3.z, 14); KQ(w3.w, 15);                     \
} while (0)

__global__ __launch_bounds__(256) void k_fused(
    const float* __restrict__ field, const float* __restrict__ quad,
    const float* __restrict__ mean_lat, const float* __restrict__ logstd_lat,
    const float* __restrict__ mean_lon, const float* __restrict__ logstd_lon,
    const float* __restrict__ mean_lev, const float* __restrict__ logstd_lev,
    const float* __restrict__ logtau, float* __restrict__ ws)
{
    const int tid = threadIdx.x;
    const int bx0 = blockIdx.x;
    // union'd LDS: qmean role uses 1024 floats as float4[256];
    // main role carves sw[2048] | wptab[256] | prm[16][8]
    __shared__ __align__(16) float smem[2432];
    __shared__ float red[4][NK];

    if (bx0 < QMEAN_BLOCKS) {
        // ---- qmean role: quad.mean(axis=0), b-split 8 ways + LDS reduce ----
        float4* sm = (float4*)smem;
        const int j4 = bx0 * 32 + (tid & 31);
        const int bg = tid >> 5;               // 8 groups of 4 b's
        const float4* q4 = (const float4*)quad;
        float4 a = make_float4(0.f, 0.f, 0.f, 0.f);
        #pragma unroll
        for (int i = 0; i < 4; ++i) {
            float4 v = q4[(size_t)(bg * 4 + i) * (YXPT / 4) + j4];
            a.x += v.x; a.y += v.y; a.z += v.z; a.w += v.w;
        }
        sm[tid] = a;
        __syncthreads();
        if (tid < 32) {
            float4 rr = sm[tid];
            #pragma unroll
            for (int g = 1; g < 8; ++g) {
                float4 v = sm[tid + 32 * g];
                rr.x += v.x; rr.y += v.y; rr.z += v.z; rr.w += v.w;
            }
            rr.x *= (1.f / BB); rr.y *= (1.f / BB);
            rr.z *= (1.f / BB); rr.w *= (1.f / BB);
            ((float4*)(ws + QMEAN_OFF))[j4] = rr;
        }
        return;
    }

    // ---- main role ----
    const int bx = bx0 - QMEAN_BLOCKS;
    // XCD-aware remap: 8 f-sharers of one quad slice -> same XCD L2
    const int qg2 = bx >> 6, f = (bx >> 3) & 7, rr0 = bx & 7;
    const int bc = qg2 * 8 + rr0;
    const int b = bc >> 3, chunk = bc & 7;
    const int wave = tid >> 6, L = tid & 63;
    const int half = L >> 5, qg = L & 31;

    const int colBase = chunk * COLS_PER_BLOCK + wave * COLS_PER_WAVE;
    const float4* fp = (const float4*)(field + (size_t)(b * NF + f) * YXPT + (size_t)colBase * PT) + L;
    const float4* qp = (const float4*)(quad  + (size_t)b * YXPT            + (size_t)colBase * PT) + L;

    // issue all 16 prologue loads FIRST: they fly during the LDS table build
    float4 fbuf[8], qbuf[8];
    #pragma unroll
    for (int j = 0; j < 8; ++j) { fbuf[j] = fp[j * STEP]; qbuf[j] = qp[j * STEP]; }

    float* sw = smem;                               // [128][16]
    float* wptab = smem + 2048;                     // [16][16]
    float (*prm)[8] = (float (*)[8])(smem + 2304);  // [16][8]

    if (tid < NK) {
        const int fk = f * NK + tid;
        prm[tid][0] = mean_lat[fk];
        prm[tid][1] = expf(-logstd_lat[fk]);            // 1/std lat
        prm[tid][2] = mean_lon[fk];
        prm[tid][3] = expf(-logstd_lon[fk]);
        prm[tid][4] = mean_lev[fk];
        prm[tid][5] = expf(-logstd_lev[fk]);
        const float itau = 1.f / (expf(logtau[fk]) + 1e-4f);
        const float rk = expf(-itau);
        prm[tid][6] = rk;                               // r = exp(-1/tau)
        prm[tid][7] = rk * rk * rk * rk;                // r^4
    }
    __syncthreads();

    #pragma unroll
    for (int i = 0; i < 8; ++i) {       // sw[col][k] for this chunk
        const int e = i * 256 + tid;
        const int col = e >> 4, k = e & 15;
        const int yx = chunk * COLS_PER_BLOCK + col;
        const float cy = -1.f + 2.f * (float)(yx >> 5) / (YY - 1);
        const float cx = -1.f + 2.f * (float)(yx & 31) / (XX - 1);
        const float zy = (cy - prm[k][0]) * prm[k][1];
        const float zx = (cx - prm[k][2]) * prm[k][3];
        sw[col * NK + k] = expf(-0.5f * (zy * zy + zx * zx));
    }
    {   // wptab[k][p]: one expf per thread
        const int k = tid >> 4, p = tid & 15;
        const float cp = -1.f + 2.f * (float)p / (PP - 1);
        const float zp = (cp - prm[k][4]) * prm[k][5];
        wptab[tid] = expf(-0.5f * zp * zp);
    }
    __syncthreads();

    // r[k] is wave-uniform -> pin to SGPRs (v_fma takes one SGPR operand)
    float r[NK];
    #pragma unroll
    for (int k = 0; k < NK; ++k)
        r[k] = __int_as_float(__builtin_amdgcn_readfirstlane(__float_as_int(prm[k][6])));

    float acc[NK];
    #pragma unroll
    for (int k = 0; k < NK; ++k) acc[k] = 0.f;

    const float* swp = sw + (wave * COLS_PER_WAVE + half) * NK;

    // distance-8: compute col-pairs 0..7 while loading 8..15
    {
        const float4* fp2 = fp + 8 * STEP;
        const float4* qp2 = qp + 8 * STEP;
        #pragma unroll
        for (int j = 0; j < 8; ++j) {
            float4 fa = fbuf[j], qa = qbuf[j];
            fbuf[j] = fp2[j * STEP]; qbuf[j] = qp2[j * STEP];
            const float4* wvp = (const float4*)(swp + j * (2 * NK));
            COLPAIR_COMPUTE(wvp);
        }
    }
    // tail: compute col-pairs 8..15 (no further prefetch)
    #pragma unroll
    for (int j = 0; j < 8; ++j) {
        float4 fa = fbuf[j], qa = qbuf[j];
        const float4* wvp = (const float4*)(swp + (8 + j) * (2 * NK));
        COLPAIR_COMPUTE(wvp);
    }

    // epilogue: apply factored per-lane constant c_k = wp[k][p] * r^t0
    // (computed HERE from LDS so it is never live across the main loop)
    {
        const int p = qg >> 1, hi = qg & 1;
        #pragma unroll
        for (int k = 0; k < NK; ++k) {
            const float wp = wptab[k * PP + p];
            const float ck = hi ? wp * prm[k][7] : wp;
            acc[k] *= ck;
        }
    }

    #pragma unroll
    for (int k = 0; k < NK; ++k) {
        float v = acc[k];
        v += __shfl_xor(v, 32); v += __shfl_xor(v, 16); v += __shfl_xor(v, 8);
        v += __shfl_xor(v, 4);  v += __shfl_xor(v, 2);  v += __shfl_xor(v, 1);
        if (L == 0) red[wave][k] = v;
    }
    __syncthreads();
    if (tid < NK) {
        float s2 = red[0][tid] + red[1][tid] + red[2][tid] + red[3][tid];
        ws[ACC_OFF + chunk * (BB * NF * NK) + (b * NF + f) * NK + tid] = s2;
    }
}

// ---------------------------------------------------------------------------
// K2: quarter-partials of integral[f,k]; block = (fk, quarter), no atomics.
// (runs after k_fused -> qmean complete by stream order)
// ---------------------------------------------------------------------------
__global__ __launch_bounds__(256) void k_integral(
    const float* __restrict__ mean_lat, const float* __restrict__ logstd_lat,
    const float* __restrict__ mean_lon, const float* __restrict__ logstd_lon,
    const float* __restrict__ mean_lev, const float* __restrict__ logstd_lev,
    const float* __restrict__ logtau, float* __restrict__ ws) {
    const int fk = blockIdx.x >> 2, qr = blockIdx.x & 3;
    const int tid = threadIdx.x;
    const float mlat = mean_lat[fk], islat = expf(-logstd_lat[fk]);
    const float mlon = mean_lon[fk], islon = expf(-logstd_lon[fk]);
    const float mlev = mean_lev[fk], islev = expf(-logstd_lev[fk]);
    const float itau = 1.f / (expf(logtau[fk]) + 1e-4f);

    __shared__ __align__(16) float wpt[PT];
    if (tid < PT) {
        const float cp = -1.f + 2.f * (float)(tid >> 3) / (PP - 1);
        const float zp = (cp - mlev) * islev;
        wpt[tid] = expf(-0.5f * zp * zp - (float)(tid & 7) * itau);
    }
    __syncthreads();

    const int yx = qr * 256 + tid;
    const float cy = -1.f + 2.f * (float)(yx >> 5) / (YY - 1);
    const float cx = -1.f + 2.f * (float)(yx & 31) / (XX - 1);
    const float zy = (cy - mlat) * islat;
    const float zx = (cx - mlon) * islon;
    const float wyx = expf(-0.5f * (zy * zy + zx * zx));

    const float4* q4 = (const float4*)(ws + QMEAN_OFF + (size_t)yx * PT);
    const float4* w4 = (const float4*)wpt;
    float s = 0.f;
    #pragma unroll
    for (int j = 0; j < PT / 4; ++j) {
        float4 w = w4[j], q = q4[j];
        s += w.x * q.x + w.y * q.y + w.z * q.z + w.w * q.w;
    }
    float partial = wyx * s;
    #pragma unroll
    for (int m = 32; m; m >>= 1) partial += __shfl_xor(partial, m);
    __shared__ float red[4];
    if ((tid & 63) == 0) red[tid >> 6] = partial;
    __syncthreads();
    if (tid == 0)
        ws[INTG_OFF + qr * (NF * NK) + fk] = red[0] + red[1] + red[2] + red[3];
}

// ---------------------------------------------------------------------------
// K3: out[b,f,k] = sum_c accP[c] / (1e-4 + sum_q intgP[q])
// ---------------------------------------------------------------------------
__global__ void k_final(const float* __restrict__ ws, float* __restrict__ out) {
    int i = blockIdx.x * 256 + threadIdx.x;
    if (i >= BB * NF * NK) return;
    float a = 0.f;
    #pragma unroll
    for (int c = 0; c < CHUNKS; ++c) a += ws[ACC_OFF + c * (BB * NF * NK) + i];
    const int fk = i & (NF * NK - 1);
    float g = 1e-4f;
    #pragma unroll
    for (int q = 0; q < 4; ++q) g += ws[INTG_OFF + q * (NF * NK) + fk];
    out[i] = a / g;
}

extern "C" void kernel_launch(void* const* d_in, const int* in_sizes, int n_in,
                              void* d_out, int out_size, void* d_ws, size_t ws_size,
                              hipStream_t stream) {
    const float* field = (const float*)d_in[0];
    const float* quad  = (const float*)d_in[1];
    float* ws = (float*)d_ws;

    k_fused<<<QMEAN_BLOCKS + BB * NF * CHUNKS, 256, 0, stream>>>(field, quad,
        (const float*)d_in[2], (const float*)d_in[3],
        (const float*)d_in[4], (const float*)d_in[5],
        (const float*)d_in[6], (const float*)d_in[7],
        (const float*)d_in[8], ws);
    k_integral<<<NF * NK * 4, 256, 0, stream>>>(
        (const float*)d_in[2], (const float*)d_in[3],
        (const float*)d_in[4], (const float*)d_in[5],
        (const float*)d_in[6], (const float*)d_in[7],
        (const float*)d_in[8], ws);
    k_final<<<(BB * NF * NK + 255) / 256, 256, 0, stream>>>(ws, (float*)d_out);
}

// Round 7
// 232.316 us; speedup vs baseline: 1.1930x; 1.1930x over previous
//
#include <hip/hip_runtime.h>
#include <math.h>

// Problem constants (fixed by reference)
#define NF 8
#define NK 16
#define BB 32
#define YY 32
#define XX 32
#define PP 16
#define TT 8
#define YX (YY*XX)     // 1024
#define PT (PP*TT)     // 128
#define YXPT (YX*PT)   // 131072
#define CHUNKS 8
#define COLS_PER_BLOCK (YX/CHUNKS)        // 128
#define COLS_PER_WAVE  (COLS_PER_BLOCK/4) // 32
#define STEP           ((2*PT)/4)         // 64 float4s = 2 columns

// Workspace layout (float offsets)
#define QMEAN_OFF 0                            // [YXPT]             = 131072
#define ACC_OFF   (QMEAN_OFF + YXPT)           // [CHUNKS][BB*NF*NK] = 32768
#define INTG_OFF  (ACC_OFF + CHUNKS*BB*NF*NK)  // [4][NF*NK]         = 512

// ---------------------------------------------------------------------------
// K1: qmean = quad.mean(axis=0). 1024 blocks, b-split 8 ways + LDS reduce.
// (R6's fusion of this into k_main REGRESSED: qmean blocks at main-role VGPR
//  + huge straight-line body -> avg occupancy 10.7%. Keep separate.)
// ---------------------------------------------------------------------------
__global__ __launch_bounds__(256) void k_qmean(const float* __restrict__ quad,
                                               float* __restrict__ ws) {
    const int tid = threadIdx.x, bx = blockIdx.x;
    __shared__ float4 sm[256];
    const int j4 = bx * 32 + (tid & 31);
    const int bg = tid >> 5;               // 8 groups of 4 b's
    const float4* q4 = (const float4*)quad;
    float4 a = make_float4(0.f, 0.f, 0.f, 0.f);
    #pragma unroll
    for (int i = 0; i < 4; ++i) {
        float4 v = q4[(size_t)(bg * 4 + i) * (YXPT / 4) + j4];
        a.x += v.x; a.y += v.y; a.z += v.z; a.w += v.w;
    }
    sm[tid] = a;
    __syncthreads();
    if (tid < 32) {
        float4 r = sm[tid];
        #pragma unroll
        for (int g = 1; g < 8; ++g) {
            float4 v = sm[tid + 32 * g];
            r.x += v.x; r.y += v.y; r.z += v.z; r.w += v.w;
        }
        r.x *= (1.f / BB); r.y *= (1.f / BB); r.z *= (1.f / BB); r.w *= (1.f / BB);
        ((float4*)(ws + QMEAN_OFF))[j4] = r;
    }
}

// ---------------------------------------------------------------------------
// K2: quarter-partials of integral[f,k]; block = (fk, quarter), no atomics.
// ---------------------------------------------------------------------------
__global__ __launch_bounds__(256) void k_integral(
    const float* __restrict__ mean_lat, const float* __restrict__ logstd_lat,
    const float* __restrict__ mean_lon, const float* __restrict__ logstd_lon,
    const float* __restrict__ mean_lev, const float* __restrict__ logstd_lev,
    const float* __restrict__ logtau, float* __restrict__ ws) {
    const int fk = blockIdx.x >> 2, qr = blockIdx.x & 3;
    const int tid = threadIdx.x;
    const float mlat = mean_lat[fk], islat = expf(-logstd_lat[fk]);
    const float mlon = mean_lon[fk], islon = expf(-logstd_lon[fk]);
    const float mlev = mean_lev[fk], islev = expf(-logstd_lev[fk]);
    const float itau = 1.f / (expf(logtau[fk]) + 1e-4f);

    __shared__ __align__(16) float wpt[PT];
    if (tid < PT) {
        const float cp = -1.f + 2.f * (float)(tid >> 3) / (PP - 1);
        const float zp = (cp - mlev) * islev;
        wpt[tid] = expf(-0.5f * zp * zp - (float)(tid & 7) * itau);
    }
    __syncthreads();

    const int yx = qr * 256 + tid;
    const float cy = -1.f + 2.f * (float)(yx >> 5) / (YY - 1);
    const float cx = -1.f + 2.f * (float)(yx & 31) / (XX - 1);
    const float zy = (cy - mlat) * islat;
    const float zx = (cx - mlon) * islon;
    const float wyx = expf(-0.5f * (zy * zy + zx * zx));

    const float4* q4 = (const float4*)(ws + QMEAN_OFF + (size_t)yx * PT);
    const float4* w4 = (const float4*)wpt;
    float s = 0.f;
    #pragma unroll
    for (int j = 0; j < PT / 4; ++j) {
        float4 w = w4[j], q = q4[j];
        s += w.x * q.x + w.y * q.y + w.z * q.z + w.w * q.w;
    }
    float partial = wyx * s;
    #pragma unroll
    for (int m = 32; m; m >>= 1) partial += __shfl_xor(partial, m);
    __shared__ float red[4];
    if ((tid & 63) == 0) red[tid >> 6] = partial;
    __syncthreads();
    if (tid == 0)
        ws[INTG_OFF + qr * (NF * NK) + fk] = red[0] + red[1] + red[2] + red[3];
}

// ---------------------------------------------------------------------------
// K3: main contraction. Block = (b, f, chunk of 128 cols); 4 waves.
//
//  R7 SINGLE CHANGE vs the proven R5 kernel (232.4us):
//  __attribute__((amdgpu_waves_per_eu(4))) -> 128-VGPR cap.
//  Evidence chain: R6 proved the allocator uses 188 VGPR when uncapped
//  (2 waves/SIMD hard cap); every round's k_main shows both pipes idle
//  (VALU ~21%, HBM ~33%) with in-flight depth ample -> the binding
//  constraint is RESIDENT WAVES. launch_bounds' 2nd arg is mis-calibrated
//  on this toolchain ((256,3) -> 84-VGPR cap = 512/6, R1/R2 spill
//  disaster); amdgpu_waves_per_eu(4) is the unambiguous 512/4=128 cap.
//  Live set post-Horner/SGPR-r/epilogue-c is ~90-110 -> fits 128 with NO
//  spill. Verification: WRITE_SIZE must stay KB-scale (MB-scale = spill =
//  back off to waves_per_eu(3)).
//
//  Carried verified decisions:
//  - distance-4 pipeline (R6's distance-8 REGRESSED: +64 VGPR, 2x code).
//  - Horner/separability: dot(ga, wf[k]) = c_k * Horner(ga, r_k); r[k]
//    wave-uniform -> SGPR via readfirstlane; c_k applied in epilogue from
//    LDS (never live across the loop). (R4/R5-verified numerics.)
//  - XCD-aware remap: 8 f-sharers of one quad slice -> same XCD L2
//    (R2-verified: FETCH 139.5 MB ~= ideal).
//  - sw/wptab/prm tables built inline in LDS (verified numerics).
//  - plain loads only (nontemporal bypasses L2 merging -> 8x over-fetch).
// ---------------------------------------------------------------------------

#define KQ(WC, K) do {                                                          \
    float poly = fmaf(ga.w, r[K], ga.z);                                        \
    poly = fmaf(poly, r[K], ga.y);                                              \
    poly = fmaf(poly, r[K], ga.x);                                              \
    acc[K] = fmaf(WC, poly, acc[K]);                                            \
} while (0)

#define COLPAIR_COMPUTE(WVP) do {                                               \
    float4 ga;                                                                  \
    ga.x = fa.x*qa.x; ga.y = fa.y*qa.y; ga.z = fa.z*qa.z; ga.w = fa.w*qa.w;     \
    float4 w0 = (WVP)[0], w1 = (WVP)[1], w2 = (WVP)[2], w3 = (WVP)[3];          \
    KQ(w0.x, 0);  KQ(w0.y, 1);  KQ(w0.z, 2);  KQ(w0.w, 3);                      \
    KQ(w1.x, 4);  KQ(w1.y, 5);  KQ(w1.z, 6);  KQ(w1.w, 7);                      \
    KQ(w2.x, 8);  KQ(w2.y, 9);  KQ(w2.z, 10); KQ(w2.w, 11);                     \
    KQ(w3.x, 12); KQ(w3.y, 13); KQ(w3.z, 14); KQ(w3.w, 15);                     \
} while (0)

__global__ __launch_bounds__(256)
__attribute__((amdgpu_waves_per_eu(4)))
void k_main(
    const float* __restrict__ field, const float* __restrict__ quad,
    const float* __restrict__ mean_lat, const float* __restrict__ logstd_lat,
    const float* __restrict__ mean_lon, const float* __restrict__ logstd_lon,
    const float* __restrict__ mean_lev, const float* __restrict__ logstd_lev,
    const float* __restrict__ logtau, float* __restrict__ ws)
{
    const int bx = blockIdx.x;
    // XCD-aware remap: 8 f-sharers of one quad slice -> same XCD L2
    const int qg2 = bx >> 6, f = (bx >> 3) & 7, rr0 = bx & 7;
    const int bc = qg2 * 8 + rr0;
    const int b = bc >> 3, chunk = bc & 7;
    const int tid = threadIdx.x;
    const int wave = tid >> 6, L = tid & 63;
    const int half = L >> 5, qg = L & 31;

    const int colBase = chunk * COLS_PER_BLOCK + wave * COLS_PER_WAVE;
    const float4* fp = (const float4*)(field + (size_t)(b * NF + f) * YXPT + (size_t)colBase * PT) + L;
    const float4* qp = (const float4*)(quad  + (size_t)b * YXPT            + (size_t)colBase * PT) + L;

    // issue prologue global loads FIRST: they fly during the LDS table build
    float4 fbuf[4], qbuf[4];
    #pragma unroll
    for (int j = 0; j < 4; ++j) { fbuf[j] = fp[j * STEP]; qbuf[j] = qp[j * STEP]; }

    __shared__ __align__(16) float sw[COLS_PER_BLOCK * NK]; // 8 KB: [col][k]
    __shared__ float wptab[NK * PP];                        // 1 KB: [k][p]
    __shared__ float prm[NK][8];

    if (tid < NK) {
        const int fk = f * NK + tid;
        prm[tid][0] = mean_lat[fk];
        prm[tid][1] = expf(-logstd_lat[fk]);            // 1/std lat
        prm[tid][2] = mean_lon[fk];
        prm[tid][3] = expf(-logstd_lon[fk]);
        prm[tid][4] = mean_lev[fk];
        prm[tid][5] = expf(-logstd_lev[fk]);
        const float itau = 1.f / (expf(logtau[fk]) + 1e-4f);
        const float rk = expf(-itau);
        prm[tid][6] = rk;                               // r = exp(-1/tau)
        prm[tid][7] = rk * rk * rk * rk;                // r^4
    }
    __syncthreads();

    #pragma unroll
    for (int i = 0; i < 8; ++i) {       // sw[col][k] for this chunk
        const int e = i * 256 + tid;
        const int col = e >> 4, k = e & 15;
        const int yx = chunk * COLS_PER_BLOCK + col;
        const float cy = -1.f + 2.f * (float)(yx >> 5) / (YY - 1);
        const float cx = -1.f + 2.f * (float)(yx & 31) / (XX - 1);
        const float zy = (cy - prm[k][0]) * prm[k][1];
        const float zx = (cx - prm[k][2]) * prm[k][3];
        sw[col * NK + k] = expf(-0.5f * (zy * zy + zx * zx));
    }
    {   // wptab[k][p]: one expf per thread
        const int k = tid >> 4, p = tid & 15;
        const float cp = -1.f + 2.f * (float)p / (PP - 1);
        const float zp = (cp - prm[k][4]) * prm[k][5];
        wptab[tid] = expf(-0.5f * zp * zp);
    }
    __syncthreads();

    // r[k] is wave-uniform -> pin to SGPRs (v_fma takes one SGPR operand)
    float r[NK];
    #pragma unroll
    for (int k = 0; k < NK; ++k)
        r[k] = __int_as_float(__builtin_amdgcn_readfirstlane(__float_as_int(prm[k][6])));

    float acc[NK];
    #pragma unroll
    for (int k = 0; k < NK; ++k) acc[k] = 0.f;

    const float* swp = sw + (wave * COLS_PER_WAVE + half) * NK;

    // distance-4 pipeline, inner-unroll-4, peeled tail (no OOB prefetch)
    #pragma unroll 1
    for (int so = 0; so < 3; ++so) {
        fp += 4 * STEP; qp += 4 * STEP;
        #pragma unroll
        for (int j = 0; j < 4; ++j) {
            float4 fa = fbuf[j], qa = qbuf[j];
            fbuf[j] = fp[j * STEP]; qbuf[j] = qp[j * STEP];
            const float4* wvp = (const float4*)(swp + j * (2 * NK));
            COLPAIR_COMPUTE(wvp);
        }
        swp += 4 * (2 * NK);
    }
    #pragma unroll
    for (int j = 0; j < 4; ++j) {
        float4 fa = fbuf[j], qa = qbuf[j];
        const float4* wvp = (const float4*)(swp + j * (2 * NK));
        COLPAIR_COMPUTE(wvp);
    }

    // epilogue: apply factored per-lane constant c_k = wp[k][p] * r^t0
    // (computed HERE from LDS so it is never live across the main loop)
    {
        const int p = qg >> 1, hi = qg & 1;
        #pragma unroll
        for (int k = 0; k < NK; ++k) {
            const float wp = wptab[k * PP + p];
            const float ck = hi ? wp * prm[k][7] : wp;
            acc[k] *= ck;
        }
    }

    __shared__ float red[4][NK];
    #pragma unroll
    for (int k = 0; k < NK; ++k) {
        float v = acc[k];
        v += __shfl_xor(v, 32); v += __shfl_xor(v, 16); v += __shfl_xor(v, 8);
        v += __shfl_xor(v, 4);  v += __shfl_xor(v, 2);  v += __shfl_xor(v, 1);
        if (L == 0) red[wave][k] = v;
    }
    __syncthreads();
    if (tid < NK) {
        float s2 = red[0][tid] + red[1][tid] + red[2][tid] + red[3][tid];
        ws[ACC_OFF + chunk * (BB * NF * NK) + (b * NF + f) * NK + tid] = s2;
    }
}

// ---------------------------------------------------------------------------
// K4: out[b,f,k] = sum_c accP[c] / (1e-4 + sum_q intgP[q])
// ---------------------------------------------------------------------------
__global__ void k_final(const float* __restrict__ ws, float* __restrict__ out) {
    int i = blockIdx.x * 256 + threadIdx.x;
    if (i >= BB * NF * NK) return;
    float a = 0.f;
    #pragma unroll
    for (int c = 0; c < CHUNKS; ++c) a += ws[ACC_OFF + c * (BB * NF * NK) + i];
    const int fk = i & (NF * NK - 1);
    float g = 1e-4f;
    #pragma unroll
    for (int q = 0; q < 4; ++q) g += ws[INTG_OFF + q * (NF * NK) + fk];
    out[i] = a / g;
}

extern "C" void kernel_launch(void* const* d_in, const int* in_sizes, int n_in,
                              void* d_out, int out_size, void* d_ws, size_t ws_size,
                              hipStream_t stream) {
    const float* field = (const float*)d_in[0];
    const float* quad  = (const float*)d_in[1];
    float* ws = (float*)d_ws;

    k_qmean<<<1024, 256, 0, stream>>>(quad, ws);
    k_integral<<<NF * NK * 4, 256, 0, stream>>>(
        (const float*)d_in[2], (const float*)d_in[3],
        (const float*)d_in[4], (const float*)d_in[5],
        (const float*)d_in[6], (const float*)d_in[7],
        (const float*)d_in[8], ws);
    k_main<<<BB * NF * CHUNKS, 256, 0, stream>>>(field, quad,
        (const float*)d_in[2], (const float*)d_in[3],
        (const float*)d_in[4], (const float*)d_in[5],
        (const float*)d_in[6], (const float*)d_in[7],
        (const float*)d_in[8], ws);
    k_final<<<(BB * NF * NK + 255) / 256, 256, 0, stream>>>(ws, (float*)d_out);
}